// Round 8
// baseline (6087.844 us; speedup 1.0000x reference)
//
#include <hip/hip_runtime.h>
#include <hip/hip_bf16.h>
#include <math.h>

typedef __bf16 bf16_t;
typedef __attribute__((ext_vector_type(8))) __bf16 bf16x8;
typedef __attribute__((ext_vector_type(4))) __bf16 bf16x4;
typedef __attribute__((ext_vector_type(4))) float f32x4;

static constexpr int B_ = 16, C_ = 16, T_ = 128, H_ = 8, L_ = 12;
static constexpr int NSEQ = C_ * T_ + 1;      // 2049
static constexpr int M_ = B_ * NSEQ;          // 32784
static constexpr int MPAD = 32896;            // 257*128
static constexpr float EPS_ = 1e-5f;

__device__ __forceinline__ float wave_sum(float s) {
    #pragma unroll
    for (int o = 1; o < 64; o <<= 1) s += __shfl_xor(s, o);
    return s;
}

// ---------------- weight conversion ----------------
__global__ void conv_qkv(const float* __restrict__ Wq, const float* __restrict__ Wk,
                         const float* __restrict__ Wv, bf16_t* __restrict__ out) {
    size_t i = (size_t)blockIdx.x * 256 + threadIdx.x;
    size_t tot = (size_t)L_ * 768 * 256;
    if (i >= tot) return;
    int k = i & 255;
    int n = (i >> 8) % 768;
    int l = i / (768 * 256);
    const float* src = (n < 256) ? Wq : (n < 512) ? Wk : Wv;
    int nn = n & 255;
    out[i] = (bf16_t)src[((size_t)l * 256 + k) * 256 + nn];
}

__global__ void conv_t(const float* __restrict__ W, bf16_t* __restrict__ out, int R, int Cc) {
    size_t i = (size_t)blockIdx.x * 256 + threadIdx.x;
    size_t tot = (size_t)L_ * R * Cc;
    if (i >= tot) return;
    int r = i % R;
    int c = (i / R) % Cc;
    int l = i / ((size_t)R * Cc);
    out[i] = (bf16_t)W[((size_t)l * R + r) * Cc + c];
}

// ---------------- embedding ----------------
__global__ void embed_kernel(const int* __restrict__ x, const float* __restrict__ emb,
                             const float* __restrict__ ch, const float* __restrict__ cls,
                             float* __restrict__ h) {
    int wave = threadIdx.x >> 6, lane = threadIdx.x & 63;
    int row = blockIdx.x * 4 + wave;
    int d0 = lane * 4;
    float4 o;
    int b = row / NSEQ, n = row % NSEQ;
    if (n == 0) {
        o = *(const float4*)(cls + d0);
    } else {
        int idx = n - 1;
        int c = idx / T_, t = idx % T_;
        int tok = x[(b * C_ + c) * T_ + t];
        float4 ev = *(const float4*)(emb + (size_t)tok * 256 + d0);
        float4 cv = *(const float4*)(ch + c * 256 + d0);
        const float kdiv = -0.03597789207803197f;   // -ln(10000)/256
        float f0 = __expf(d0 * kdiv);
        float f2 = __expf((d0 + 2) * kdiv);
        float a0 = t * f0, a2 = t * f2;
        o.x = ev.x + cv.x + sinf(a0);
        o.y = ev.y + cv.y + cosf(a0);
        o.z = ev.z + cv.z + sinf(a2);
        o.w = ev.w + cv.w + cosf(a2);
    }
    *(float4*)(h + (size_t)row * 256 + d0) = o;
}

// ============================================================================
// Fused LN1 + QKV GEMM.  One block = 128-row stripe, 8 waves.
// A = layer_norm(h) staged ONCE into swizzled LDS (64 KB, one barrier);
// main loop over 6 col-tiles is BARRIER-FREE, weights streamed L2->reg.
// Output in head-major layout: q/k/v [b*8+h][n][32] for dense attention reads.
// ============================================================================
__launch_bounds__(512)
__global__ void fused_qkv(const float* __restrict__ hsrc, const float* __restrict__ lng,
                          const float* __restrict__ lnb, const bf16_t* __restrict__ Wt,
                          bf16_t* __restrict__ qa, bf16_t* __restrict__ ka,
                          bf16_t* __restrict__ va) {
    __shared__ bf16_t yn[128 * 256];
    int tid = threadIdx.x;
    int row0 = blockIdx.x * 128;
    {
        int row = tid >> 2, q4 = tid & 3;
        int grow = row0 + row;
        bool ok = grow < M_;
        const float* rp = hsrc + (size_t)grow * 256;
        float v[64];
        float sum = 0.f, sq = 0.f;
        #pragma unroll
        for (int j = 0; j < 16; ++j) {
            float4 t = ok ? *(const float4*)(rp + (q4 + j * 4) * 4)
                          : float4{0.f, 0.f, 0.f, 0.f};
            v[j*4+0] = t.x; v[j*4+1] = t.y; v[j*4+2] = t.z; v[j*4+3] = t.w;
            sum += t.x + t.y + t.z + t.w;
            sq  += t.x*t.x + t.y*t.y + t.z*t.z + t.w*t.w;
        }
        sum += __shfl_xor(sum, 1); sum += __shfl_xor(sum, 2);
        sq  += __shfl_xor(sq, 1);  sq  += __shfl_xor(sq, 2);
        float mean = sum * (1.f/256.f);
        float var  = sq * (1.f/256.f) - mean*mean;
        float rs = rsqrtf(var + EPS_);
        int sx = row & 7;
        #pragma unroll
        for (int j = 0; j < 16; ++j) {
            int ce = q4 + j * 4;          // 4-elem group 0..63
            int colb = ce * 4;
            float4 gv = *(const float4*)(lng + colb);
            float4 bv = *(const float4*)(lnb + colb);
            bf16x4 o4;
            o4[0] = (bf16_t)((v[j*4+0]-mean)*rs*gv.x + bv.x);
            o4[1] = (bf16_t)((v[j*4+1]-mean)*rs*gv.y + bv.y);
            o4[2] = (bf16_t)((v[j*4+2]-mean)*rs*gv.z + bv.z);
            o4[3] = (bf16_t)((v[j*4+3]-mean)*rs*gv.w + bv.w);
            int cg = ce >> 1, hf = ce & 1;
            *(bf16x4*)(&yn[row*256 + ((cg ^ sx) << 3) + hf*4]) = o4;
        }
    }
    __syncthreads();

    int lane = tid & 63, wave = tid >> 6;
    int l15 = lane & 15, ksel = lane >> 4;
    // precompute store row decomposition: soff = b*8*NSEQ + n  (= 8r - 7n)
    int soff[8][4];
    #pragma unroll
    for (int m = 0; m < 8; ++m)
        #pragma unroll
        for (int i = 0; i < 4; ++i) {
            int r = row0 + m*16 + ksel*4 + i;
            int n = r % NSEQ;
            soff[m][i] = 8*r - 7*n;
        }

    for (int ct = 0; ct < 6; ++ct) {
        int col = ct*128 + wave*16 + l15;
        const bf16_t* bp = Wt + (size_t)col * 256 + ksel * 8;
        f32x4 acc[8] = {};
        #pragma unroll
        for (int kk = 0; kk < 8; ++kk) {
            bf16x8 bf = *(const bf16x8*)(bp + kk*32);
            #pragma unroll
            for (int m = 0; m < 8; ++m) {
                int r = m*16 + l15;
                bf16x8 af = *(const bf16x8*)(&yn[r*256 + (((kk*4+ksel) ^ (r&7)) << 3)]);
                acc[m] = __builtin_amdgcn_mfma_f32_16x16x32_bf16(af, bf, acc[m], 0, 0, 0);
            }
        }
        int sel = col >> 8, hh = (col >> 5) & 7, dh = col & 31;
        bf16_t* ob = (sel == 0) ? qa : (sel == 1) ? ka : va;
        int hoff = hh * NSEQ;
        #pragma unroll
        for (int m = 0; m < 8; ++m)
            #pragma unroll
            for (int i = 0; i < 4; ++i) {
                int r = row0 + m*16 + ksel*4 + i;
                if (r < M_)
                    ob[((size_t)(soff[m][i] + hoff)) * 32 + dh] = (bf16_t)acc[m][i];
            }
    }
}

// ============================================================================
// Fused Wo GEMM + bias + residual (h += att @ Wo^T + bo).  Same structure.
// ============================================================================
__launch_bounds__(512)
__global__ void fused_wo(const bf16_t* __restrict__ att, const bf16_t* __restrict__ Wt,
                         const float* __restrict__ bias, float* __restrict__ hio) {
    __shared__ bf16_t yn[128 * 256];
    int tid = threadIdx.x;
    int row0 = blockIdx.x * 128;
    {
        int row = tid >> 2, q4 = tid & 3;
        const bf16_t* rp = att + (size_t)(row0 + row) * 256;
        int sx = row & 7;
        #pragma unroll
        for (int j = 0; j < 8; ++j) {
            int cg = q4 + j * 4;       // 16B chunk 0..31
            bf16x8 t = *(const bf16x8*)(rp + cg * 8);
            *(bf16x8*)(&yn[row*256 + ((cg ^ sx) << 3)]) = t;
        }
    }
    __syncthreads();
    int lane = tid & 63, wave = tid >> 6;
    int l15 = lane & 15, ksel = lane >> 4;
    for (int ct = 0; ct < 2; ++ct) {
        int col = ct*128 + wave*16 + l15;
        const bf16_t* bp = Wt + (size_t)col*256 + ksel*8;
        f32x4 acc[8] = {};
        #pragma unroll
        for (int kk = 0; kk < 8; ++kk) {
            bf16x8 bf = *(const bf16x8*)(bp + kk*32);
            #pragma unroll
            for (int m = 0; m < 8; ++m) {
                int r = m*16 + l15;
                bf16x8 af = *(const bf16x8*)(&yn[r*256 + (((kk*4+ksel) ^ (r&7)) << 3)]);
                acc[m] = __builtin_amdgcn_mfma_f32_16x16x32_bf16(af, bf, acc[m], 0, 0, 0);
            }
        }
        float bv = bias[col];
        #pragma unroll
        for (int m = 0; m < 8; ++m)
            #pragma unroll
            for (int i = 0; i < 4; ++i) {
                int r = row0 + m*16 + ksel*4 + i;
                if (r < M_) hio[(size_t)r*256 + col] += acc[m][i] + bv;
            }
    }
}

// ============================================================================
// Fused LN2 + FF1 + GELU + FF2 + residual.  One block = 128-row stripe.
// yn (LN output, 64 KB) resident; per 128-wide ff-chunk: p = gelu(yn@W1c)
// bounced through 32 KB LDS; out-acc[128][256] in registers across chunks.
// Two barriers per chunk; weights streamed L2->reg.
// ============================================================================
__launch_bounds__(512)
__global__ void fused_ff(const float* __restrict__ hsrc, const float* __restrict__ lng,
                         const float* __restrict__ lnb, const bf16_t* __restrict__ W1t,
                         const float* __restrict__ b1v, const bf16_t* __restrict__ W2t,
                         const float* __restrict__ b2v, float* __restrict__ hio) {
    __shared__ bf16_t yn[128 * 256];
    __shared__ bf16_t ps[128 * 128];
    int tid = threadIdx.x;
    int row0 = blockIdx.x * 128;
    {
        int row = tid >> 2, q4 = tid & 3;
        int grow = row0 + row;
        bool ok = grow < M_;
        const float* rp = hsrc + (size_t)grow * 256;
        float v[64];
        float sum = 0.f, sq = 0.f;
        #pragma unroll
        for (int j = 0; j < 16; ++j) {
            float4 t = ok ? *(const float4*)(rp + (q4 + j * 4) * 4)
                          : float4{0.f, 0.f, 0.f, 0.f};
            v[j*4+0] = t.x; v[j*4+1] = t.y; v[j*4+2] = t.z; v[j*4+3] = t.w;
            sum += t.x + t.y + t.z + t.w;
            sq  += t.x*t.x + t.y*t.y + t.z*t.z + t.w*t.w;
        }
        sum += __shfl_xor(sum, 1); sum += __shfl_xor(sum, 2);
        sq  += __shfl_xor(sq, 1);  sq  += __shfl_xor(sq, 2);
        float mean = sum * (1.f/256.f);
        float var  = sq * (1.f/256.f) - mean*mean;
        float rs = rsqrtf(var + EPS_);
        int sx = row & 7;
        #pragma unroll
        for (int j = 0; j < 16; ++j) {
            int ce = q4 + j * 4;
            int colb = ce * 4;
            float4 gv = *(const float4*)(lng + colb);
            float4 bv = *(const float4*)(lnb + colb);
            bf16x4 o4;
            o4[0] = (bf16_t)((v[j*4+0]-mean)*rs*gv.x + bv.x);
            o4[1] = (bf16_t)((v[j*4+1]-mean)*rs*gv.y + bv.y);
            o4[2] = (bf16_t)((v[j*4+2]-mean)*rs*gv.z + bv.z);
            o4[3] = (bf16_t)((v[j*4+3]-mean)*rs*gv.w + bv.w);
            int cg = ce >> 1, hf = ce & 1;
            *(bf16x4*)(&yn[row*256 + ((cg ^ sx) << 3) + hf*4]) = o4;
        }
    }
    __syncthreads();

    int lane = tid & 63, wave = tid >> 6;
    int l15 = lane & 15, ksel = lane >> 4;
    int pcol = wave*16 + l15;
    int pc = pcol >> 3, pe = pcol & 7;
    f32x4 oacc[8][2] = {};

    for (int kc = 0; kc < 8; ++kc) {
        int fcol = kc*128 + pcol;
        const bf16_t* bp = W1t + (size_t)fcol*256 + ksel*8;
        f32x4 pacc[8] = {};
        #pragma unroll
        for (int kk = 0; kk < 8; ++kk) {
            bf16x8 bf = *(const bf16x8*)(bp + kk*32);
            #pragma unroll
            for (int m = 0; m < 8; ++m) {
                int r = m*16 + l15;
                bf16x8 af = *(const bf16x8*)(&yn[r*256 + (((kk*4+ksel) ^ (r&7)) << 3)]);
                pacc[m] = __builtin_amdgcn_mfma_f32_16x16x32_bf16(af, bf, pacc[m], 0, 0, 0);
            }
        }
        float b1s = b1v[fcol];
        #pragma unroll
        for (int m = 0; m < 8; ++m)
            #pragma unroll
            for (int i = 0; i < 4; ++i) {
                int rr = m*16 + ksel*4 + i;
                float vv = pacc[m][i] + b1s;
                float gl = 0.5f * vv * (1.f + erff(vv * 0.70710678118654752f));
                ps[rr*128 + ((pc ^ (rr&7)) << 3) + pe] = (bf16_t)gl;
            }
        __syncthreads();
        int oc = wave*32 + l15;
        const bf16_t* b2p0 = W2t + (size_t)oc*1024 + kc*128 + ksel*8;
        const bf16_t* b2p1 = b2p0 + (size_t)16*1024;
        #pragma unroll
        for (int k2 = 0; k2 < 4; ++k2) {
            bf16x8 bf0 = *(const bf16x8*)(b2p0 + k2*32);
            bf16x8 bf1 = *(const bf16x8*)(b2p1 + k2*32);
            #pragma unroll
            for (int m = 0; m < 8; ++m) {
                int r = m*16 + l15;
                bf16x8 af = *(const bf16x8*)(&ps[r*128 + (((k2*4+ksel) ^ (r&7)) << 3)]);
                oacc[m][0] = __builtin_amdgcn_mfma_f32_16x16x32_bf16(af, bf0, oacc[m][0], 0, 0, 0);
                oacc[m][1] = __builtin_amdgcn_mfma_f32_16x16x32_bf16(af, bf1, oacc[m][1], 0, 0, 0);
            }
        }
        __syncthreads();
    }

    #pragma unroll
    for (int m = 0; m < 8; ++m)
        #pragma unroll
        for (int nf = 0; nf < 2; ++nf) {
            int col = wave*32 + nf*16 + l15;
            float bv = b2v[col];
            #pragma unroll
            for (int i = 0; i < 4; ++i) {
                int r = row0 + m*16 + ksel*4 + i;
                if (r < M_) hio[(size_t)r*256 + col] += oacc[m][nf][i] + bv;
            }
        }
}

// ---------------- k column max (head-major layout: dense) ----------------
__global__ void kmax_kernel(const bf16_t* __restrict__ karr, float* __restrict__ colmax) {
    int bh = blockIdx.x;
    const bf16_t* kb = karr + (size_t)bh * NSEQ * 32;
    int c = threadIdx.x & 31, stripe = threadIdx.x >> 5;
    float m = -1e30f;
    for (int n = stripe; n < NSEQ; n += 8)
        m = fmaxf(m, (float)kb[(size_t)n * 32 + c]);
    __shared__ float red[8][32];
    red[stripe][c] = m;
    __syncthreads();
    if (threadIdx.x < 32) {
        float mm = red[0][c];
        #pragma unroll
        for (int s2 = 1; s2 < 8; ++s2) mm = fmaxf(mm, red[s2][c]);
        colmax[bh * 32 + c] = mm;
    }
}

// ---------------- ctx partial: sum_n exp(k-max)*v ; colsum ----------------
__global__ void ctx_kernel(const bf16_t* __restrict__ karr, const bf16_t* __restrict__ varr,
                           const float* __restrict__ colmax,
                           float* __restrict__ ctx_part, float* __restrict__ colsum_part) {
    int blk = blockIdx.x;                // bh*8 + s
    int bh = blk >> 3, s = blk & 7;
    int n0 = s * 257, n1 = min(n0 + 257, NSEQ);
    int d = threadIdx.x & 31, eg = threadIdx.x >> 5;
    float maxd = colmax[bh * 32 + d];
    float acc[4] = {0.f, 0.f, 0.f, 0.f};
    float ksum = 0.f;
    __shared__ float ks[64][32];
    __shared__ float vs[64][32];
    const bf16_t* kb = karr + (size_t)bh * NSEQ * 32;
    const bf16_t* vb = varr + (size_t)bh * NSEQ * 32;
    int lr = threadIdx.x >> 2, lc = (threadIdx.x & 3) * 8;
    for (int c0 = n0; c0 < n1; c0 += 64) {
        int rows = min(64, n1 - c0);
        if (lr < rows) {
            bf16x8 kv8 = *(const bf16x8*)(kb + (size_t)(c0 + lr) * 32 + lc);
            bf16x8 vv8 = *(const bf16x8*)(vb + (size_t)(c0 + lr) * 32 + lc);
            #pragma unroll
            for (int j = 0; j < 8; ++j) {
                ks[lr][lc + j] = (float)kv8[j];
                vs[lr][lc + j] = (float)vv8[j];
            }
        }
        __syncthreads();
        for (int r = 0; r < rows; ++r) {
            float ek = __expf(ks[r][d] - maxd);
            if (eg == 0) ksum += ek;
            const float* vr = &vs[r][eg * 4];
            acc[0] += ek * vr[0]; acc[1] += ek * vr[1];
            acc[2] += ek * vr[2]; acc[3] += ek * vr[3];
        }
        __syncthreads();
    }
    float* cp = ctx_part + ((size_t)blk * 32 + d) * 32 + eg * 4;
    cp[0] = acc[0]; cp[1] = acc[1]; cp[2] = acc[2]; cp[3] = acc[3];
    if (eg == 0) colsum_part[blk * 32 + d] = ksum;
}

// ---------------- o = softmax(q)*scale @ ctx  -> bf16 att [M][256] ----------------
__global__ void o_kernel(const bf16_t* __restrict__ qarr, const float* __restrict__ ctx_part,
                         const float* __restrict__ colsum_part, bf16_t* __restrict__ att) {
    int bh = blockIdx.x, b = bh >> 3, hh = bh & 7;
    int chunk = blockIdx.y;
    __shared__ float ctx[1024];
    __shared__ float csum[32];
    int t = threadIdx.x;
    if (t < 32) {
        float s = 0.f;
        #pragma unroll
        for (int ss = 0; ss < 8; ++ss) s += colsum_part[(bh * 8 + ss) * 32 + t];
        csum[t] = s;
    }
    __syncthreads();
    for (int i = t; i < 1024; i += 256) {
        float s = 0.f;
        #pragma unroll
        for (int ss = 0; ss < 8; ++ss) s += ctx_part[(size_t)(bh * 8 + ss) * 1024 + i];
        ctx[i] = s / csum[i >> 5];
    }
    __syncthreads();
    int e = t & 31, grp = t >> 5;
    int n0 = chunk * 228, n1 = min(n0 + 228, NSEQ);
    for (int n = n0 + grp; n < n1; n += 8) {
        const bf16_t* q = qarr + ((size_t)bh * NSEQ + n) * 32;
        float qv = (float)q[e];
        float mx = qv;
        #pragma unroll
        for (int o2 = 16; o2 > 0; o2 >>= 1) mx = fmaxf(mx, __shfl_xor(mx, o2, 32));
        float ev = __expf(qv - mx);
        float sm = ev;
        #pragma unroll
        for (int o2 = 16; o2 > 0; o2 >>= 1) sm += __shfl_xor(sm, o2, 32);
        float p = ev * 0.17677669529663689f / sm;   // dh^-0.5 / sum
        float s = 0.f;
        #pragma unroll
        for (int dd = 0; dd < 32; ++dd) s += __shfl(p, dd, 32) * ctx[dd * 32 + e];
        att[(size_t)(b * NSEQ + n) * 256 + hh * 32 + e] = (bf16_t)s;
    }
}

// ---------------- classifier head: one wave per (b, cls) ----------------
__global__ void head_kernel(const float* __restrict__ h, const float* __restrict__ Wh,
                            const float* __restrict__ bh, float* __restrict__ out) {
    int idx = blockIdx.x;                 // 0..79 = b*5 + c
    int b = idx / 5, c = idx % 5;
    int lane = threadIdx.x;
    const float* xp = h + (size_t)b * NSEQ * 256;
    float s = 0.f;
    #pragma unroll
    for (int d0 = 0; d0 < 256; d0 += 64) s += xp[d0 + lane] * Wh[(d0 + lane) * 5 + c];
    s = wave_sum(s);
    if (lane == 0) out[idx] = s + bh[c];
}

extern "C" void kernel_launch(void* const* d_in, const int* in_sizes, int n_in,
                              void* d_out, int out_size, void* d_ws, size_t ws_size,
                              hipStream_t stream) {
    const int*   x    = (const int*)d_in[0];
    const float* emb  = (const float*)d_in[1];
    const float* ch   = (const float*)d_in[2];
    const float* cls  = (const float*)d_in[3];
    const float* Wq   = (const float*)d_in[4];
    const float* Wk   = (const float*)d_in[5];
    const float* Wv   = (const float*)d_in[6];
    const float* Wo   = (const float*)d_in[7];
    const float* bo   = (const float*)d_in[8];
    const float* g1   = (const float*)d_in[9];
    const float* b1   = (const float*)d_in[10];
    const float* W1   = (const float*)d_in[11];
    const float* bf1  = (const float*)d_in[12];
    const float* W2   = (const float*)d_in[13];
    const float* bf2  = (const float*)d_in[14];
    const float* g2   = (const float*)d_in[15];
    const float* b2   = (const float*)d_in[16];
    const float* Wh   = (const float*)d_in[17];
    const float* bh   = (const float*)d_in[18];

    char* ws = (char*)d_ws;
    size_t off = 0;
    float*  h      = (float*)(ws + off);  off += (size_t)M_ * 256 * 4;            // 33,570,816
    bf16_t* att    = (bf16_t*)(ws + off); off += (size_t)MPAD * 256 * 2;          // 16,842,752
    bf16_t* qa     = (bf16_t*)(ws + off); off += (size_t)M_ * 256 * 2;            // 16,785,408
    bf16_t* ka     = (bf16_t*)(ws + off); off += (size_t)M_ * 256 * 2;            // 16,785,408
    bf16_t* va     = (bf16_t*)(ws + off); off += (size_t)M_ * 256 * 2;            // 16,785,408
    float*  ctxp   = (float*)(ws + off);  off += (size_t)16 * 8 * 8 * 1024 * 4;   // 4,194,304
    float*  csump  = (float*)(ws + off);  off += (size_t)16 * 8 * 8 * 32 * 4;     // 131,072
    float*  cmax   = (float*)(ws + off);  off += (size_t)16 * 8 * 32 * 4;         // 16,384
    bf16_t* wqkv_t = (bf16_t*)(ws + off); off += (size_t)L_ * 768 * 256 * 2;      // 4,718,592
    bf16_t* wo_t   = (bf16_t*)(ws + off); off += (size_t)L_ * 256 * 256 * 2;      // 1,572,864
    bf16_t* w1_t   = (bf16_t*)(ws + off); off += (size_t)L_ * 1024 * 256 * 2;     // 6,291,456
    bf16_t* w2_t   = (bf16_t*)(ws + off); off += (size_t)L_ * 256 * 1024 * 2;     // 6,291,456
    (void)ws_size; (void)in_sizes; (void)n_in; (void)out_size;

    conv_qkv<<<9216, 256, 0, stream>>>(Wq, Wk, Wv, wqkv_t);
    conv_t<<<3072, 256, 0, stream>>>(Wo, wo_t, 256, 256);
    conv_t<<<12288, 256, 0, stream>>>(W1, w1_t, 256, 1024);
    conv_t<<<12288, 256, 0, stream>>>(W2, w2_t, 1024, 256);

    embed_kernel<<<M_ / 4, 256, 0, stream>>>(x, emb, ch, cls, h);

    for (int l = 0; l < L_; ++l) {
        fused_qkv<<<257, 512, 0, stream>>>(h, g1 + l * 256, b1 + l * 256,
                                           wqkv_t + (size_t)l * 768 * 256, qa, ka, va);
        kmax_kernel<<<128, 256, 0, stream>>>(ka, cmax);
        ctx_kernel<<<1024, 256, 0, stream>>>(ka, va, cmax, ctxp, csump);
        o_kernel<<<dim3(128, 9), 256, 0, stream>>>(qa, ctxp, csump, att);
        fused_wo<<<257, 512, 0, stream>>>(att, wo_t + (size_t)l * 256 * 256,
                                          bo + l * 256, h);
        fused_ff<<<257, 512, 0, stream>>>(h, g2 + l * 256, b2 + l * 256,
                                          w1_t + (size_t)l * 1024 * 256, bf1 + l * 1024,
                                          w2_t + (size_t)l * 256 * 1024, bf2 + l * 256, h);
    }

    head_kernel<<<80, 64, 0, stream>>>(h, Wh, bh, (float*)d_out);
}

// Round 9
// 4425.377 us; speedup vs baseline: 1.3757x; 1.3757x over previous
//
#include <hip/hip_runtime.h>
#include <hip/hip_bf16.h>
#include <math.h>

typedef __bf16 bf16_t;
typedef __attribute__((ext_vector_type(8))) __bf16 bf16x8;
typedef __attribute__((ext_vector_type(4))) __bf16 bf16x4;
typedef __attribute__((ext_vector_type(4))) float f32x4;

static constexpr int B_ = 16, C_ = 16, T_ = 128, H_ = 8, L_ = 12;
static constexpr int NSEQ = C_ * T_ + 1;      // 2049
static constexpr int M_ = B_ * NSEQ;          // 32784
static constexpr int MPAD = 32896;            // 257*128
static constexpr float EPS_ = 1e-5f;

__device__ __forceinline__ float wave_sum(float s) {
    #pragma unroll
    for (int o = 1; o < 64; o <<= 1) s += __shfl_xor(s, o);
    return s;
}

// ---------------- weight conversion to W' layout [L][K/8][N][8] ----------------
__global__ void conv_w(const float* __restrict__ W, bf16_t* __restrict__ out, int K, int N) {
    size_t i = (size_t)blockIdx.x * 256 + threadIdx.x;
    size_t per = (size_t)K * N;
    size_t tot = (size_t)L_ * per;
    if (i >= tot) return;
    int kl = i & 7;
    size_t r = i >> 3;
    int n = r % N;
    size_t r2 = r / N;
    int kh = r2 % (K >> 3);
    int l = r2 / (K >> 3);
    out[i] = (bf16_t)W[(size_t)l * per + (size_t)(kh * 8 + kl) * N + n];
}

__global__ void conv_wq3(const float* __restrict__ Wq, const float* __restrict__ Wk,
                         const float* __restrict__ Wv, bf16_t* __restrict__ out) {
    size_t i = (size_t)blockIdx.x * 256 + threadIdx.x;
    size_t tot = (size_t)L_ * 32 * 768 * 8;
    if (i >= tot) return;
    int kl = i & 7;
    size_t r = i >> 3;
    int n = r % 768;
    size_t r2 = r / 768;
    int kh = r2 % 32;
    int l = r2 / 32;
    const float* src = (n < 256) ? Wq : (n < 512) ? Wk : Wv;
    out[i] = (bf16_t)src[(size_t)l * 65536 + (size_t)(kh * 8 + kl) * 256 + (n & 255)];
}

// ---------------- embedding ----------------
__global__ void embed_kernel(const int* __restrict__ x, const float* __restrict__ emb,
                             const float* __restrict__ ch, const float* __restrict__ cls,
                             float* __restrict__ h) {
    int wave = threadIdx.x >> 6, lane = threadIdx.x & 63;
    int row = blockIdx.x * 4 + wave;
    int d0 = lane * 4;
    float4 o;
    int b = row / NSEQ, n = row % NSEQ;
    if (n == 0) {
        o = *(const float4*)(cls + d0);
    } else {
        int idx = n - 1;
        int c = idx / T_, t = idx % T_;
        int tok = x[(b * C_ + c) * T_ + t];
        float4 ev = *(const float4*)(emb + (size_t)tok * 256 + d0);
        float4 cv = *(const float4*)(ch + c * 256 + d0);
        const float kdiv = -0.03597789207803197f;   // -ln(10000)/256
        float f0 = __expf(d0 * kdiv);
        float f2 = __expf((d0 + 2) * kdiv);
        float a0 = t * f0, a2 = t * f2;
        o.x = ev.x + cv.x + sinf(a0);
        o.y = ev.y + cv.y + cosf(a0);
        o.z = ev.z + cv.z + sinf(a2);
        o.w = ev.w + cv.w + cosf(a2);
    }
    *(float4*)(h + (size_t)row * 256 + d0) = o;
}

// ============================================================================
// A-resident barrier-free GEMM.  Block = 128-row stripe (8 waves, 512 thr).
// A (optionally layer-normed) staged ONCE into 64KB swizzled LDS; ONE barrier;
// then NT col-tiles, weights streamed L2->reg from W' [K/8][N][8] layout
// (quarter-wave B-fragment loads = 256B contiguous -> L2-friendly).
// SRC 0: A = layer_norm(h fp32)      SRC 1: A = bf16 [MPAD][256]
// EPI 0: Cb = bf16(acc)  EPI 1: Cf += acc+bias  EPI 2: Cb = bf16(gelu(acc+bias))
// ============================================================================
template <int SRC, int EPI, int NT>
__launch_bounds__(512)
__global__ void gemm_ar(const void* __restrict__ Asrc, const float* __restrict__ lng,
                        const float* __restrict__ lnb, const bf16_t* __restrict__ Wp,
                        const float* __restrict__ bias, float* __restrict__ Cf,
                        bf16_t* __restrict__ Cb, int N) {
    __shared__ bf16_t yn[128 * 256];
    int tid = threadIdx.x;
    int row0 = blockIdx.y * 128;
    int row = tid >> 2, q4 = tid & 3;
    int sx = row & 7;

    if (SRC == 0) {
        const float* rp = (const float*)Asrc + (size_t)(row0 + row) * 256;
        bool ok = (row0 + row) < M_;
        float v[64];
        float sum = 0.f, sq = 0.f;
        #pragma unroll
        for (int j = 0; j < 16; ++j) {
            float4 t = ok ? *(const float4*)(rp + (q4 + j * 4) * 4)
                          : float4{0.f, 0.f, 0.f, 0.f};
            v[j*4+0] = t.x; v[j*4+1] = t.y; v[j*4+2] = t.z; v[j*4+3] = t.w;
            sum += t.x + t.y + t.z + t.w;
            sq  += t.x*t.x + t.y*t.y + t.z*t.z + t.w*t.w;
        }
        sum += __shfl_xor(sum, 1); sum += __shfl_xor(sum, 2);
        sq  += __shfl_xor(sq, 1);  sq  += __shfl_xor(sq, 2);
        float mean = sum * (1.f/256.f);
        float var  = sq * (1.f/256.f) - mean*mean;
        float rs = rsqrtf(var + EPS_);
        #pragma unroll
        for (int j = 0; j < 16; ++j) {
            int ce = q4 + j * 4;
            int colb = ce * 4;
            float4 gv = *(const float4*)(lng + colb);
            float4 bv = *(const float4*)(lnb + colb);
            bf16x4 o4;
            o4[0] = (bf16_t)((v[j*4+0]-mean)*rs*gv.x + bv.x);
            o4[1] = (bf16_t)((v[j*4+1]-mean)*rs*gv.y + bv.y);
            o4[2] = (bf16_t)((v[j*4+2]-mean)*rs*gv.z + bv.z);
            o4[3] = (bf16_t)((v[j*4+3]-mean)*rs*gv.w + bv.w);
            int cg = ce >> 1, hf = ce & 1;
            *(bf16x4*)(&yn[row*256 + ((cg ^ sx) << 3) + hf*4]) = o4;
        }
    } else {
        const bf16_t* rp = (const bf16_t*)Asrc + (size_t)(row0 + row) * 256;
        #pragma unroll
        for (int j = 0; j < 8; ++j) {
            int cg = q4 * 8 + j;
            bf16x8 t = *(const bf16x8*)(rp + cg * 8);
            *(bf16x8*)(&yn[row*256 + ((cg ^ sx) << 3)]) = t;
        }
    }
    __syncthreads();

    int lane = tid & 63, wave = tid >> 6;
    int l15 = lane & 15, ksel = lane >> 4;
    #pragma unroll
    for (int t = 0; t < NT; ++t) {
        int col = (blockIdx.x * NT + t) * 128 + wave * 16 + l15;
        const bf16_t* bp = Wp + ((size_t)ksel * N + col) * 8;
        f32x4 acc[8] = {};
        #pragma unroll
        for (int kk = 0; kk < 8; ++kk) {
            bf16x8 bf = *(const bf16x8*)(bp + (size_t)kk * 32 * N);
            #pragma unroll
            for (int m = 0; m < 8; ++m) {
                int r = m * 16 + l15;
                bf16x8 af = *(const bf16x8*)(&yn[r*256 + (((kk*4+ksel) ^ (r&7)) << 3)]);
                acc[m] = __builtin_amdgcn_mfma_f32_16x16x32_bf16(af, bf, acc[m], 0, 0, 0);
            }
        }
        float bv = (EPI != 0) ? bias[col] : 0.f;
        #pragma unroll
        for (int m = 0; m < 8; ++m)
            #pragma unroll
            for (int i = 0; i < 4; ++i) {
                int r = row0 + m * 16 + ksel * 4 + i;
                if (r < M_) {
                    float v = acc[m][i] + bv;
                    if (EPI == 0) {
                        Cb[(size_t)r * N + col] = (bf16_t)v;
                    } else if (EPI == 1) {
                        Cf[(size_t)r * N + col] += v;
                    } else {
                        float gl = 0.5f * v * (1.f + erff(v * 0.70710678118654752f));
                        Cb[(size_t)r * N + col] = (bf16_t)gl;
                    }
                }
            }
    }
}

// ============================================================================
// FF2 chunked: h += f1[MPAD][1024] @ W2'^ + bias.  Output tile 128x128.
// 4 K-chunks of 256: stage 64KB f1-chunk (swizzled), compute; 8 barriers total.
// ============================================================================
__launch_bounds__(512)
__global__ void gemm_ff2c(const bf16_t* __restrict__ f1, const bf16_t* __restrict__ W2p,
                          const float* __restrict__ bias, float* __restrict__ hio) {
    __shared__ bf16_t as[128 * 256];
    int tid = threadIdx.x;
    int row0 = blockIdx.y * 128;
    int lane = tid & 63, wave = tid >> 6;
    int l15 = lane & 15, ksel = lane >> 4;
    int col = blockIdx.x * 128 + wave * 16 + l15;
    int row = tid >> 2, q4 = tid & 3;
    int sx = row & 7;
    const bf16_t* rp = f1 + (size_t)(row0 + row) * 1024;
    f32x4 acc[8] = {};

    for (int c = 0; c < 4; ++c) {
        if (c) __syncthreads();
        #pragma unroll
        for (int j = 0; j < 8; ++j) {
            int cg = q4 * 8 + j;
            bf16x8 t = *(const bf16x8*)(rp + c * 256 + cg * 8);
            *(bf16x8*)(&as[row*256 + ((cg ^ sx) << 3)]) = t;
        }
        __syncthreads();
        const bf16_t* bp = W2p + ((size_t)(c * 32 + ksel) * 256 + col) * 8;
        #pragma unroll
        for (int kk = 0; kk < 8; ++kk) {
            bf16x8 bf = *(const bf16x8*)(bp + (size_t)kk * 32 * 256);
            #pragma unroll
            for (int m = 0; m < 8; ++m) {
                int r = m * 16 + l15;
                bf16x8 af = *(const bf16x8*)(&as[r*256 + (((kk*4+ksel) ^ (r&7)) << 3)]);
                acc[m] = __builtin_amdgcn_mfma_f32_16x16x32_bf16(af, bf, acc[m], 0, 0, 0);
            }
        }
    }

    float bv = bias[col];
    #pragma unroll
    for (int m = 0; m < 8; ++m)
        #pragma unroll
        for (int i = 0; i < 4; ++i) {
            int r = row0 + m * 16 + ksel * 4 + i;
            if (r < M_) hio[(size_t)r * 256 + col] += acc[m][i] + bv;
        }
}

// ---------------- k column max (over n) ----------------
__global__ void kmax_kernel(const bf16_t* __restrict__ qkv, float* __restrict__ colmax) {
    int bh = blockIdx.x;                 // b*8+h
    int b = bh >> 3, hh = bh & 7;
    int c = threadIdx.x & 31, stripe = threadIdx.x >> 5;
    const bf16_t* base = qkv + (size_t)b * NSEQ * 768 + 256 + hh * 32;
    float m = -1e30f;
    for (int n = stripe; n < NSEQ; n += 8)
        m = fmaxf(m, (float)base[(size_t)n * 768 + c]);
    __shared__ float red[8][32];
    red[stripe][c] = m;
    __syncthreads();
    if (threadIdx.x < 32) {
        float mm = red[0][c];
        #pragma unroll
        for (int s2 = 1; s2 < 8; ++s2) mm = fmaxf(mm, red[s2][c]);
        colmax[bh * 32 + c] = mm;
    }
}

// ---------------- ctx partial: sum_n exp(k-max)*v ; colsum ----------------
__global__ void ctx_kernel(const bf16_t* __restrict__ qkv, const float* __restrict__ colmax,
                           float* __restrict__ ctx_part, float* __restrict__ colsum_part) {
    int blk = blockIdx.x;                // bh*8 + s
    int bh = blk >> 3, s = blk & 7;
    int b = bh >> 3, hh = bh & 7;
    int n0 = s * 257, n1 = min(n0 + 257, NSEQ);
    int d = threadIdx.x & 31, eg = threadIdx.x >> 5;
    float maxd = colmax[bh * 32 + d];
    float acc[4] = {0.f, 0.f, 0.f, 0.f};
    float ksum = 0.f;
    __shared__ float ks[64][32];
    __shared__ float vs[64][32];
    const bf16_t* kbase = qkv + (size_t)b * NSEQ * 768 + 256 + hh * 32;
    const bf16_t* vbase = kbase + 256;
    int lr = threadIdx.x >> 2, lc = (threadIdx.x & 3) * 8;
    for (int c0 = n0; c0 < n1; c0 += 64) {
        int rows = min(64, n1 - c0);
        if (lr < rows) {
            bf16x8 kv8 = *(const bf16x8*)(kbase + (size_t)(c0 + lr) * 768 + lc);
            bf16x8 vv8 = *(const bf16x8*)(vbase + (size_t)(c0 + lr) * 768 + lc);
            #pragma unroll
            for (int j = 0; j < 8; ++j) {
                ks[lr][lc + j] = (float)kv8[j];
                vs[lr][lc + j] = (float)vv8[j];
            }
        }
        __syncthreads();
        for (int r = 0; r < rows; ++r) {
            float ek = __expf(ks[r][d] - maxd);
            if (eg == 0) ksum += ek;
            const float* vr = &vs[r][eg * 4];
            acc[0] += ek * vr[0]; acc[1] += ek * vr[1];
            acc[2] += ek * vr[2]; acc[3] += ek * vr[3];
        }
        __syncthreads();
    }
    float* cp = ctx_part + ((size_t)blk * 32 + d) * 32 + eg * 4;
    cp[0] = acc[0]; cp[1] = acc[1]; cp[2] = acc[2]; cp[3] = acc[3];
    if (eg == 0) colsum_part[blk * 32 + d] = ksum;
}

// ---------------- o = softmax(q)*scale @ ctx  -> bf16 att [M][256] ----------------
__global__ void o_kernel(const bf16_t* __restrict__ qkv, const float* __restrict__ ctx_part,
                         const float* __restrict__ colsum_part, bf16_t* __restrict__ att) {
    int bh = blockIdx.x, b = bh >> 3, hh = bh & 7;
    int chunk = blockIdx.y;
    __shared__ float ctx[1024];
    __shared__ float csum[32];
    int t = threadIdx.x;
    if (t < 32) {
        float s = 0.f;
        #pragma unroll
        for (int ss = 0; ss < 8; ++ss) s += colsum_part[(bh * 8 + ss) * 32 + t];
        csum[t] = s;
    }
    __syncthreads();
    for (int i = t; i < 1024; i += 256) {
        float s = 0.f;
        #pragma unroll
        for (int ss = 0; ss < 8; ++ss) s += ctx_part[(size_t)(bh * 8 + ss) * 1024 + i];
        ctx[i] = s / csum[i >> 5];
    }
    __syncthreads();
    int e = t & 31, grp = t >> 5;
    int n0 = chunk * 228, n1 = min(n0 + 228, NSEQ);
    for (int n = n0 + grp; n < n1; n += 8) {
        const bf16_t* q = qkv + (size_t)(b * NSEQ + n) * 768 + hh * 32;
        float qv = (float)q[e];
        float mx = qv;
        #pragma unroll
        for (int o2 = 16; o2 > 0; o2 >>= 1) mx = fmaxf(mx, __shfl_xor(mx, o2, 32));
        float ev = __expf(qv - mx);
        float sm = ev;
        #pragma unroll
        for (int o2 = 16; o2 > 0; o2 >>= 1) sm += __shfl_xor(sm, o2, 32);
        float p = ev * 0.17677669529663689f / sm;   // dh^-0.5 / sum
        float s = 0.f;
        #pragma unroll
        for (int dd = 0; dd < 32; ++dd) s += __shfl(p, dd, 32) * ctx[dd * 32 + e];
        att[(size_t)(b * NSEQ + n) * 256 + hh * 32 + e] = (bf16_t)s;
    }
}

// ---------------- classifier head: one wave per (b, cls) ----------------
__global__ void head_kernel(const float* __restrict__ h, const float* __restrict__ Wh,
                            const float* __restrict__ bh, float* __restrict__ out) {
    int idx = blockIdx.x;                 // 0..79 = b*5 + c
    int b = idx / 5, c = idx % 5;
    int lane = threadIdx.x;
    const float* xp = h + (size_t)b * NSEQ * 256;
    float s = 0.f;
    #pragma unroll
    for (int d0 = 0; d0 < 256; d0 += 64) s += xp[d0 + lane] * Wh[(d0 + lane) * 5 + c];
    s = wave_sum(s);
    if (lane == 0) out[idx] = s + bh[c];
}

extern "C" void kernel_launch(void* const* d_in, const int* in_sizes, int n_in,
                              void* d_out, int out_size, void* d_ws, size_t ws_size,
                              hipStream_t stream) {
    const int*   x    = (const int*)d_in[0];
    const float* emb  = (const float*)d_in[1];
    const float* ch   = (const float*)d_in[2];
    const float* cls  = (const float*)d_in[3];
    const float* Wq   = (const float*)d_in[4];
    const float* Wk   = (const float*)d_in[5];
    const float* Wv   = (const float*)d_in[6];
    const float* Wo   = (const float*)d_in[7];
    const float* bo   = (const float*)d_in[8];
    const float* g1   = (const float*)d_in[9];
    const float* b1   = (const float*)d_in[10];
    const float* W1   = (const float*)d_in[11];
    const float* bf1  = (const float*)d_in[12];
    const float* W2   = (const float*)d_in[13];
    const float* bf2  = (const float*)d_in[14];
    const float* g2   = (const float*)d_in[15];
    const float* b2   = (const float*)d_in[16];
    const float* Wh   = (const float*)d_in[17];
    const float* bh   = (const float*)d_in[18];

    char* ws = (char*)d_ws;
    size_t off = 0;
    float*  h      = (float*)(ws + off);  off += (size_t)M_ * 256 * 4;            // 33,570,816
    bf16_t* att    = (bf16_t*)(ws + off); off += (size_t)MPAD * 256 * 2;          // 16,842,752
    bf16_t* qkv    = (bf16_t*)(ws + off);
    bf16_t* f1     = (bf16_t*)(ws + off); off += (size_t)MPAD * 1024 * 2;         // 67,371,008 (f1 aliases qkv)
    float*  ctxp   = (float*)(ws + off);  off += (size_t)16 * 8 * 8 * 1024 * 4;   // 4,194,304
    float*  csump  = (float*)(ws + off);  off += (size_t)16 * 8 * 8 * 32 * 4;     // 131,072
    float*  cmax   = (float*)(ws + off);  off += (size_t)16 * 8 * 32 * 4;         // 16,384
    bf16_t* wqkv_p = (bf16_t*)(ws + off); off += (size_t)L_ * 768 * 256 * 2;      // 4,718,592
    bf16_t* wo_p   = (bf16_t*)(ws + off); off += (size_t)L_ * 256 * 256 * 2;      // 1,572,864
    bf16_t* w1_p   = (bf16_t*)(ws + off); off += (size_t)L_ * 1024 * 256 * 2;     // 6,291,456
    bf16_t* w2_p   = (bf16_t*)(ws + off); off += (size_t)L_ * 256 * 1024 * 2;     // 6,291,456
    (void)ws_size; (void)in_sizes; (void)n_in; (void)out_size;

    conv_wq3<<<9216, 256, 0, stream>>>(Wq, Wk, Wv, wqkv_p);
    conv_w<<<3072, 256, 0, stream>>>(Wo, wo_p, 256, 256);
    conv_w<<<12288, 256, 0, stream>>>(W1, w1_p, 256, 1024);
    conv_w<<<12288, 256, 0, stream>>>(W2, w2_p, 1024, 256);

    embed_kernel<<<M_ / 4, 256, 0, stream>>>(x, emb, ch, cls, h);

    for (int l = 0; l < L_; ++l) {
        // LN1 + QKV -> qkv bf16 [M][768]
        gemm_ar<0, 0, 3><<<dim3(2, 257), 512, 0, stream>>>(
            h, g1 + l * 256, b1 + l * 256, wqkv_p + (size_t)l * 768 * 256,
            nullptr, nullptr, qkv, 768);
        kmax_kernel<<<128, 256, 0, stream>>>(qkv, cmax);
        ctx_kernel<<<1024, 256, 0, stream>>>(qkv, cmax, ctxp, csump);
        o_kernel<<<dim3(128, 9), 256, 0, stream>>>(qkv, ctxp, csump, att);
        // Wo + bias + residual
        gemm_ar<1, 1, 1><<<dim3(2, 257), 512, 0, stream>>>(
            att, nullptr, nullptr, wo_p + (size_t)l * 256 * 256,
            bo + l * 256, h, nullptr, 256);
        // LN2 + FF1 + GELU -> f1 bf16 [M][1024]
        gemm_ar<0, 2, 4><<<dim3(2, 257), 512, 0, stream>>>(
            h, g2 + l * 256, b2 + l * 256, w1_p + (size_t)l * 1024 * 256,
            bf1 + l * 1024, nullptr, f1, 1024);
        // FF2 + bias + residual
        gemm_ff2c<<<dim3(2, 257), 512, 0, stream>>>(
            f1, w2_p + (size_t)l * 256 * 1024, bf2 + l * 256, h);
    }

    head_kernel<<<80, 64, 0, stream>>>(h, Wh, bh, (float*)d_out);
}